// Round 1
// baseline (574.999 us; speedup 1.0000x reference)
//
#include <hip/hip_runtime.h>
#include <hip/hip_bf16.h>

typedef short bf16x8 __attribute__((ext_vector_type(8)));
typedef float f32x4 __attribute__((ext_vector_type(4)));
typedef unsigned short u16;

#define DN 128   // node in props
#define DE 32    // edge in props
#define LE 16    // latent edges (channels)
#define LN 64    // latent nodes
#define DOUT 128 // out props

__device__ inline u16 f2bf(float f) {
  unsigned u = __float_as_uint(f);
  unsigned r = (u + 0x7FFFu + ((u >> 16) & 1u)) >> 16;
  return (u16)r;
}

// ep[E,16] = relu(edge_attr[E,32] @ W_edge[32,16] + b_edge)
__global__ __launch_bounds__(256) void k_edge_props(const float* __restrict__ ea,
    const float* __restrict__ We, const float* __restrict__ be,
    float* __restrict__ ep, int E) {
  int e = blockIdx.x * 256 + threadIdx.x;
  if (e >= E) return;
  const float4* a4 = (const float4*)(ea + (size_t)e * DE);
  float a[DE];
#pragma unroll
  for (int j = 0; j < DE / 4; ++j) {
    float4 v = a4[j];
    a[4*j] = v.x; a[4*j+1] = v.y; a[4*j+2] = v.z; a[4*j+3] = v.w;
  }
  float acc[LE];
#pragma unroll
  for (int l = 0; l < LE; ++l) acc[l] = be[l];
#pragma unroll
  for (int k = 0; k < DE; ++k) {
    float av = a[k];
#pragma unroll
    for (int l = 0; l < LE; ++l) acc[l] = fmaf(av, We[k * LE + l], acc[l]);
  }
  float4* o4 = (float4*)(ep + (size_t)e * LE);
#pragma unroll
  for (int j = 0; j < LE / 4; ++j) {
    float4 v;
    v.x = fmaxf(acc[4*j+0], 0.f); v.y = fmaxf(acc[4*j+1], 0.f);
    v.z = fmaxf(acc[4*j+2], 0.f); v.w = fmaxf(acc[4*j+3], 0.f);
    o4[j] = v;
  }
}

// fp32 -> bf16 bulk convert (4 elems/thread)
__global__ __launch_bounds__(256) void k_f2bf(const float* __restrict__ in,
                                              u16* __restrict__ outp, int n4) {
  int i = blockIdx.x * 256 + threadIdx.x;
  if (i >= n4) return;
  float4 v = ((const float4*)in)[i];
  short4 o;
  o.x = (short)f2bf(v.x); o.y = (short)f2bf(v.y);
  o.z = (short)f2bf(v.z); o.w = (short)f2bf(v.w);
  ((short4*)outp)[i] = o;
}

// Pack fp32 W[K,NCOL] into bf16 MFMA-B fragments:
// dst[((nt*KT+kt)*64+lane)*8+i] = W[kt*32+(lane>>4)*8+i][nt*16+(lane&15)]
__global__ __launch_bounds__(256) void k_packb(const float* __restrict__ W,
                                               u16* __restrict__ Bp, int K, int NCOL) {
  int NT = NCOL >> 4, KT = K >> 5;
  int total = NT * KT * 64;
  int idx = blockIdx.x * 256 + threadIdx.x;
  if (idx >= total) return;
  int lane = idx & 63;
  int rest = idx >> 6;
  int kt = rest % KT, nt = rest / KT;
  int col = nt * 16 + (lane & 15);
  int kb = kt * 32 + (lane >> 4) * 8;
  u16* dst = Bp + (size_t)idx * 8;
#pragma unroll
  for (int i = 0; i < 8; ++i) dst[i] = f2bf(W[(size_t)(kb + i) * NCOL + col]);
}

__global__ __launch_bounds__(256) void k_count(const int* __restrict__ ei,
                                               int* __restrict__ cnt, int E) {
  int e = blockIdx.x * 256 + threadIdx.x;
  if (e < E) atomicAdd(&cnt[ei[E + e]], 1);
}

// single-block exclusive scan over cnt[0..N) -> offs[0..N]
__global__ __launch_bounds__(1024) void k_scan(const int* __restrict__ cnt,
                                               int* __restrict__ offs, int N) {
  __shared__ int wsum[16];
  int t = threadIdx.x;
  int chunk = (N + 1023) >> 10;
  int s0 = t * chunk;
  int s1 = min(s0 + chunk, N);
  int s = 0;
  for (int i = s0; i < s1; ++i) s += cnt[i];
  int lane = t & 63, wid = t >> 6;
  int v = s;
#pragma unroll
  for (int d = 1; d < 64; d <<= 1) {
    int u = __shfl_up(v, d);
    if (lane >= d) v += u;
  }
  if (lane == 63) wsum[wid] = v;
  __syncthreads();
  if (t == 0) {
    int run = 0;
    for (int w = 0; w < 16; ++w) { int xv = wsum[w]; wsum[w] = run; run += xv; }
  }
  __syncthreads();
  int run = v - s + wsum[wid];  // exclusive prefix for this thread
  for (int i = s0; i < s1; ++i) { offs[i] = run; run += cnt[i]; }
  if (s1 == N && s0 < N) offs[N] = run;
}

__global__ __launch_bounds__(256) void k_fill(const int* __restrict__ ei,
    int* __restrict__ cur, const int* __restrict__ offs, int* __restrict__ se, int E) {
  int e = blockIdx.x * 256 + threadIdx.x;
  if (e >= E) return;
  int c = ei[E + e];
  int p = atomicAdd(&cur[c], 1);
  se[offs[c] + p] = e;
}

// dinv[n,l] = rsqrt(1 + sum_{e into n} ep[e,l])
__global__ __launch_bounds__(256) void k_dinv(const float* __restrict__ ep,
    const int* __restrict__ offs, const int* __restrict__ se,
    float* __restrict__ dinv, int N) {
  int t = threadIdx.x;
  int n = blockIdx.x * 16 + (t >> 4);
  int l = t & 15;
  if (n >= N) return;
  int i0 = offs[n], i1 = offs[n + 1];
  float s = 1.0f;  // self loop weight
  for (int i = i0; i < i1; ++i) s += ep[(size_t)se[i] * LE + l];
  dinv[(size_t)n * LE + l] = rsqrtf(s);
}

// feats[n, l*64+c] = b_gcn[c] + dinv[n,l]^2 * xW[n,c]
//                  + sum_{e into n} dinv[row,l]*ep[e,l]*dinv[n,l] * xW[row,c]
// one block per node; thread t: l = t>>4, cols (t&15)*4..+3; bf16 output
__global__ __launch_bounds__(256) void k_feats(const int* __restrict__ ei,
    const float* __restrict__ ep, const float* __restrict__ dinv,
    const float* __restrict__ xw, const float* __restrict__ bgcn,
    const int* __restrict__ offs, const int* __restrict__ se,
    u16* __restrict__ feats, int N) {
  int n = blockIdx.x;
  int t = threadIdx.x;
  int l = t >> 4, cq = t & 15;
  float dn = dinv[(size_t)n * LE + l];
  float4 xs = *(const float4*)(xw + (size_t)n * LN + cq * 4);
  float4 bg = *(const float4*)(bgcn + cq * 4);
  float sn = dn * dn;  // self-loop norm = dinv*1*dinv
  float ax = fmaf(sn, xs.x, bg.x);
  float ay = fmaf(sn, xs.y, bg.y);
  float az = fmaf(sn, xs.z, bg.z);
  float aw = fmaf(sn, xs.w, bg.w);
  int i1 = offs[n + 1];
  for (int i = offs[n]; i < i1; ++i) {
    int e = se[i];
    int r = ei[e];
    float w = ep[(size_t)e * LE + l];
    float dr = dinv[(size_t)r * LE + l];
    float4 xv = *(const float4*)(xw + (size_t)r * LN + cq * 4);
    float nm = dr * w * dn;
    ax = fmaf(nm, xv.x, ax); ay = fmaf(nm, xv.y, ay);
    az = fmaf(nm, xv.z, az); aw = fmaf(nm, xv.w, aw);
  }
  short4 o;
  o.x = (short)f2bf(ax); o.y = (short)f2bf(ay);
  o.z = (short)f2bf(az); o.w = (short)f2bf(aw);
  *(short4*)(feats + (size_t)n * (LE * LN) + l * LN + cq * 4) = o;
}

// C[M,NCOL] = A[M,K](bf16) @ Bpacked(bf16) (+bias, relu if FIN), fp32 out
// block: 4 waves, BM=64 (wave = 16 rows x NCOL cols)
template <int K, int NCOL, bool FIN>
__global__ __launch_bounds__(256) void k_gemm(const u16* __restrict__ A,
    const u16* __restrict__ Bp, const float* __restrict__ bias,
    float* __restrict__ outp, int M) {
  constexpr int NT = NCOL / 16;
  constexpr int KT = K / 32;
  int lane = threadIdx.x & 63;
  int wid = threadIdx.x >> 6;
  int m0 = blockIdx.x * 64 + wid * 16;
  f32x4 acc[NT];
#pragma unroll
  for (int nt = 0; nt < NT; ++nt) {
    acc[nt][0] = 0.f; acc[nt][1] = 0.f; acc[nt][2] = 0.f; acc[nt][3] = 0.f;
  }
  int arow = m0 + (lane & 15);
  bool aval = arow < M;
  const u16* ab = A + (size_t)arow * K + (lane >> 4) * 8;
#pragma unroll 4
  for (int kt = 0; kt < KT; ++kt) {
    bf16x8 a;
#pragma unroll
    for (int i = 0; i < 8; ++i) a[i] = 0;
    if (aval) a = *(const bf16x8*)(ab + kt * 32);
#pragma unroll
    for (int nt = 0; nt < NT; ++nt) {
      bf16x8 b = *(const bf16x8*)(Bp + ((size_t)(nt * KT + kt) * 64 + lane) * 8);
      acc[nt] = __builtin_amdgcn_mfma_f32_16x16x32_bf16(a, b, acc[nt], 0, 0, 0);
    }
  }
  int rb = m0 + ((lane >> 4) << 2);
  int col0 = lane & 15;
#pragma unroll
  for (int nt = 0; nt < NT; ++nt) {
    int c = nt * 16 + col0;
    float bb = FIN ? bias[c] : 0.f;
#pragma unroll
    for (int r = 0; r < 4; ++r) {
      int row = rb + r;
      if (row < M) {
        float vv = acc[nt][r] + bb;
        if (FIN) vv = fmaxf(vv, 0.f);
        outp[(size_t)row * NCOL + c] = vv;
      }
    }
  }
}

extern "C" void kernel_launch(void* const* d_in, const int* in_sizes, int n_in,
                              void* d_out, int out_size, void* d_ws, size_t ws_size,
                              hipStream_t stream) {
  const float* x  = (const float*)d_in[0];
  const int*   ei = (const int*)d_in[1];
  const float* ea = (const float*)d_in[2];
  const float* Wg = (const float*)d_in[3];
  const float* bg = (const float*)d_in[4];
  const float* We = (const float*)d_in[5];
  const float* be = (const float*)d_in[6];
  const float* Wn = (const float*)d_in[7];
  const float* bn = (const float*)d_in[8];
  float* outp = (float*)d_out;
  int N = in_sizes[0] / DN;  // 50000
  int E = in_sizes[1] / 2;   // 800000

  char* p = (char*)d_ws;
  auto carve = [&](size_t bytes) {
    char* r = p;
    p += (bytes + 255) & ~(size_t)255;
    return (void*)r;
  };
  float* ep    = (float*)carve((size_t)E * LE * 4);
  float* xw    = (float*)carve((size_t)N * LN * 4);
  float* dinv  = (float*)carve((size_t)N * LE * 4);
  u16*   feats = (u16*)carve((size_t)N * (LE * LN) * 2);
  u16*   xb    = (u16*)carve((size_t)N * DN * 2);
  u16*   WnP   = (u16*)carve((size_t)(LE * LN) * DOUT * 2);
  u16*   WgP   = (u16*)carve((size_t)DN * LN * 2);
  int*   offs  = (int*)carve((size_t)(N + 1) * 4);
  int*   cnt   = (int*)carve((size_t)N * 4);
  int*   cur   = (int*)carve((size_t)N * 4);
  int*   se    = (int*)carve((size_t)E * 4);

  hipMemsetAsync(cnt, 0, (size_t)N * 4, stream);
  hipMemsetAsync(cur, 0, (size_t)N * 4, stream);

  k_edge_props<<<(E + 255) / 256, 256, 0, stream>>>(ea, We, be, ep, E);
  k_f2bf<<<((N * DN / 4) + 255) / 256, 256, 0, stream>>>(x, xb, N * DN / 4);
  k_packb<<<(((DN / 32) * (LN / 16) * 64) + 255) / 256, 256, 0, stream>>>(Wg, WgP, DN, LN);
  k_packb<<<((((LE * LN) / 32) * (DOUT / 16) * 64) + 255) / 256, 256, 0, stream>>>(Wn, WnP, LE * LN, DOUT);
  k_gemm<DN, LN, false><<<(N + 63) / 64, 256, 0, stream>>>(xb, WgP, nullptr, xw, N);
  k_count<<<(E + 255) / 256, 256, 0, stream>>>(ei, cnt, E);
  k_scan<<<1, 1024, 0, stream>>>(cnt, offs, N);
  k_fill<<<(E + 255) / 256, 256, 0, stream>>>(ei, cur, offs, se, E);
  k_dinv<<<(N + 15) / 16, 256, 0, stream>>>(ep, offs, se, dinv, N);
  k_feats<<<N, 256, 0, stream>>>(ei, ep, dinv, xw, bg, offs, se, feats, N);
  k_gemm<LE * LN, DOUT, true><<<(N + 63) / 64, 256, 0, stream>>>(feats, WnP, bn, outp, N);
}

// Round 2
// 460.824 us; speedup vs baseline: 1.2478x; 1.2478x over previous
//
#include <hip/hip_runtime.h>
#include <hip/hip_bf16.h>

typedef short bf16x8 __attribute__((ext_vector_type(8)));
typedef float f32x4 __attribute__((ext_vector_type(4)));
typedef unsigned short u16;

#define DN 128   // node in props
#define DE 32    // edge in props
#define LE 16    // latent edges (channels)
#define LN 64    // latent nodes
#define DOUT 128 // out props

__device__ inline u16 f2bf(float f) {
  unsigned u = __float_as_uint(f);
  unsigned r = (u + 0x7FFFu + ((u >> 16) & 1u)) >> 16;
  return (u16)r;
}

// w[epos[e], l] = relu(edge_attr[e,:] @ W_edge + b_edge)[l]  (CSR-ordered write)
__global__ __launch_bounds__(256) void k_edge_props(const float* __restrict__ ea,
    const float* __restrict__ We, const float* __restrict__ be,
    const int* __restrict__ epos, float* __restrict__ w, int E) {
  int e = blockIdx.x * 256 + threadIdx.x;
  if (e >= E) return;
  const float4* a4 = (const float4*)(ea + (size_t)e * DE);
  float a[DE];
#pragma unroll
  for (int j = 0; j < DE / 4; ++j) {
    float4 v = a4[j];
    a[4*j] = v.x; a[4*j+1] = v.y; a[4*j+2] = v.z; a[4*j+3] = v.w;
  }
  float acc[LE];
#pragma unroll
  for (int l = 0; l < LE; ++l) acc[l] = be[l];
#pragma unroll
  for (int k = 0; k < DE; ++k) {
    float av = a[k];
#pragma unroll
    for (int l = 0; l < LE; ++l) acc[l] = fmaf(av, We[k * LE + l], acc[l]);
  }
  float4* o4 = (float4*)(w + (size_t)epos[e] * LE);
#pragma unroll
  for (int j = 0; j < LE / 4; ++j) {
    float4 v;
    v.x = fmaxf(acc[4*j+0], 0.f); v.y = fmaxf(acc[4*j+1], 0.f);
    v.z = fmaxf(acc[4*j+2], 0.f); v.w = fmaxf(acc[4*j+3], 0.f);
    o4[j] = v;
  }
}

// fp32 -> bf16 bulk convert (4 elems/thread)
__global__ __launch_bounds__(256) void k_f2bf(const float* __restrict__ in,
                                              u16* __restrict__ outp, int n4) {
  int i = blockIdx.x * 256 + threadIdx.x;
  if (i >= n4) return;
  float4 v = ((const float4*)in)[i];
  short4 o;
  o.x = (short)f2bf(v.x); o.y = (short)f2bf(v.y);
  o.z = (short)f2bf(v.z); o.w = (short)f2bf(v.w);
  ((short4*)outp)[i] = o;
}

// Pack fp32 W[K,NCOL] into bf16 MFMA-B fragments:
// dst[((nt*KT+kt)*64+lane)*8+i] = W[kt*32+(lane>>4)*8+i][nt*16+(lane&15)]
__global__ __launch_bounds__(256) void k_packb(const float* __restrict__ W,
                                               u16* __restrict__ Bp, int K, int NCOL) {
  int NT = NCOL >> 4, KT = K >> 5;
  int total = NT * KT * 64;
  int idx = blockIdx.x * 256 + threadIdx.x;
  if (idx >= total) return;
  int lane = idx & 63;
  int rest = idx >> 6;
  int kt = rest % KT, nt = rest / KT;
  int col = nt * 16 + (lane & 15);
  int kb = kt * 32 + (lane >> 4) * 8;
  u16* dst = Bp + (size_t)idx * 8;
#pragma unroll
  for (int i = 0; i < 8; ++i) dst[i] = f2bf(W[(size_t)(kb + i) * NCOL + col]);
}

__global__ __launch_bounds__(256) void k_count(const int* __restrict__ ei,
                                               int* __restrict__ cnt, int E) {
  int e = blockIdx.x * 256 + threadIdx.x;
  if (e < E) atomicAdd(&cnt[ei[E + e]], 1);
}

// single-block exclusive scan over cnt[0..N) -> offs[0..N]
__global__ __launch_bounds__(1024) void k_scan(const int* __restrict__ cnt,
                                               int* __restrict__ offs, int N) {
  __shared__ int wsum[16];
  int t = threadIdx.x;
  int chunk = (N + 1023) >> 10;
  int s0 = t * chunk;
  int s1 = min(s0 + chunk, N);
  int s = 0;
  for (int i = s0; i < s1; ++i) s += cnt[i];
  int lane = t & 63, wid = t >> 6;
  int v = s;
#pragma unroll
  for (int d = 1; d < 64; d <<= 1) {
    int u = __shfl_up(v, d);
    if (lane >= d) v += u;
  }
  if (lane == 63) wsum[wid] = v;
  __syncthreads();
  if (t == 0) {
    int run = 0;
    for (int w = 0; w < 16; ++w) { int xv = wsum[w]; wsum[w] = run; run += xv; }
  }
  __syncthreads();
  int run = v - s + wsum[wid];  // exclusive prefix for this thread
  for (int i = s0; i < s1; ++i) { offs[i] = run; run += cnt[i]; }
  if (s1 == N && s0 < N) offs[N] = run;
}

// epos[e] = CSR slot of edge e; src[slot] = source node of that edge
__global__ __launch_bounds__(256) void k_fill(const int* __restrict__ ei,
    int* __restrict__ cur, const int* __restrict__ offs,
    int* __restrict__ epos, int* __restrict__ src, int E) {
  int e = blockIdx.x * 256 + threadIdx.x;
  if (e >= E) return;
  int c = ei[E + e];
  int p = atomicAdd(&cur[c], 1);
  int pos = offs[c] + p;
  epos[e] = pos;
  src[pos] = ei[e];
}

// dinv[n,l] = rsqrt(1 + sum over CSR segment of w[i,l])  (contiguous reads)
__global__ __launch_bounds__(256) void k_dinv(const float* __restrict__ w,
    const int* __restrict__ offs, float* __restrict__ dinv, int N) {
  int t = threadIdx.x;
  int n = blockIdx.x * 16 + (t >> 4);
  int l = t & 15;
  if (n >= N) return;
  int i0 = offs[n], i1 = offs[n + 1];
  float s = 1.0f;  // self loop weight
  for (int i = i0; i < i1; ++i) s += w[(size_t)i * LE + l];
  dinv[(size_t)n * LE + l] = rsqrtf(s);
}

// fold source normalization: w[pos,l] *= dinv[src[pos],l]
__global__ __launch_bounds__(256) void k_wsc(float* __restrict__ w,
    const int* __restrict__ src, const float* __restrict__ dinv, int T) {
  int idx = blockIdx.x * 256 + threadIdx.x;
  int pos = idx >> 4, l = idx & 15;
  if (pos >= T) return;
  int s = src[pos];
  w[(size_t)pos * LE + l] *= dinv[(size_t)s * LE + l];
}

// feats[n, l*64+c] = bf16( b_gcn[c] + dn*(sum_i wsc[i,l]*xW[src_i,c]) + dn^2*xW[n,c] )
// one WAVE per node; lane = (l = lane&15, col group g = lane>>4 covering 16 cols)
__global__ __launch_bounds__(256) void k_feats2(const int* __restrict__ src,
    const float* __restrict__ wsc, const float* __restrict__ dinv,
    const float* __restrict__ xw, const float* __restrict__ bgcn,
    const int* __restrict__ offs, u16* __restrict__ feats, int N) {
  int wid = threadIdx.x >> 6;
  int n = blockIdx.x * 4 + wid;
  if (n >= N) return;
  int lane = threadIdx.x & 63;
  int l = lane & 15, g = lane >> 4;
  float dn = dinv[(size_t)n * LE + l];
  const float* xbase = xw + g * 16;
  float acc[16];
#pragma unroll
  for (int j = 0; j < 16; ++j) acc[j] = 0.f;
  int i0 = offs[n], i1 = offs[n + 1];
  int scur = (i0 < i1) ? src[i0] : 0;
#pragma unroll 2
  for (int i = i0; i < i1; ++i) {
    const float4* xr = (const float4*)(xbase + (size_t)scur * LN);
    float4 x0 = xr[0], x1 = xr[1], x2 = xr[2], x3 = xr[3];
    float wv = wsc[(size_t)i * LE + l];
    int snext = (i + 1 < i1) ? src[i + 1] : 0;
    acc[0]  = fmaf(wv, x0.x, acc[0]);  acc[1]  = fmaf(wv, x0.y, acc[1]);
    acc[2]  = fmaf(wv, x0.z, acc[2]);  acc[3]  = fmaf(wv, x0.w, acc[3]);
    acc[4]  = fmaf(wv, x1.x, acc[4]);  acc[5]  = fmaf(wv, x1.y, acc[5]);
    acc[6]  = fmaf(wv, x1.z, acc[6]);  acc[7]  = fmaf(wv, x1.w, acc[7]);
    acc[8]  = fmaf(wv, x2.x, acc[8]);  acc[9]  = fmaf(wv, x2.y, acc[9]);
    acc[10] = fmaf(wv, x2.z, acc[10]); acc[11] = fmaf(wv, x2.w, acc[11]);
    acc[12] = fmaf(wv, x3.x, acc[12]); acc[13] = fmaf(wv, x3.y, acc[13]);
    acc[14] = fmaf(wv, x3.z, acc[14]); acc[15] = fmaf(wv, x3.w, acc[15]);
    scur = snext;
  }
  float dn2 = dn * dn;
  const float4* xs4 = (const float4*)(xw + (size_t)n * LN + g * 16);
  const float4* bg4 = (const float4*)(bgcn + g * 16);
  u16* ob = feats + (size_t)n * (LE * LN) + l * LN + g * 16;
#pragma unroll
  for (int q = 0; q < 4; ++q) {
    float4 xs = xs4[q];
    float4 bg = bg4[q];
    short4 o;
    o.x = (short)f2bf(bg.x + dn * acc[4*q+0] + dn2 * xs.x);
    o.y = (short)f2bf(bg.y + dn * acc[4*q+1] + dn2 * xs.y);
    o.z = (short)f2bf(bg.z + dn * acc[4*q+2] + dn2 * xs.z);
    o.w = (short)f2bf(bg.w + dn * acc[4*q+3] + dn2 * xs.w);
    *(short4*)(ob + q * 4) = o;
  }
}

// C[M,NCOL] = A[M,K](bf16) @ Bpacked(bf16) (+bias, relu if FIN), fp32 out
// block: 4 waves, 32 rows/wave (MT=2), 128 rows/block
template <int K, int NCOL, bool FIN>
__global__ __launch_bounds__(256) void k_gemm(const u16* __restrict__ A,
    const u16* __restrict__ Bp, const float* __restrict__ bias,
    float* __restrict__ outp, int M) {
  constexpr int NT = NCOL / 16;
  constexpr int KT = K / 32;
  int lane = threadIdx.x & 63;
  int wid = threadIdx.x >> 6;
  int m0 = blockIdx.x * 128 + wid * 32;
  f32x4 acc[2][NT];
#pragma unroll
  for (int mt = 0; mt < 2; ++mt)
#pragma unroll
    for (int nt = 0; nt < NT; ++nt) {
      acc[mt][nt][0] = 0.f; acc[mt][nt][1] = 0.f;
      acc[mt][nt][2] = 0.f; acc[mt][nt][3] = 0.f;
    }
  int r0 = m0 + (lane & 15);
  int r1 = r0 + 16;
  bool v0 = r0 < M, v1 = r1 < M;
  const u16* ab0 = A + (size_t)r0 * K + (lane >> 4) * 8;
  const u16* ab1 = A + (size_t)r1 * K + (lane >> 4) * 8;
#pragma unroll 4
  for (int kt = 0; kt < KT; ++kt) {
    bf16x8 a0, a1;
#pragma unroll
    for (int i = 0; i < 8; ++i) { a0[i] = 0; a1[i] = 0; }
    if (v0) a0 = *(const bf16x8*)(ab0 + kt * 32);
    if (v1) a1 = *(const bf16x8*)(ab1 + kt * 32);
#pragma unroll
    for (int nt = 0; nt < NT; ++nt) {
      bf16x8 b = *(const bf16x8*)(Bp + ((size_t)(nt * KT + kt) * 64 + lane) * 8);
      acc[0][nt] = __builtin_amdgcn_mfma_f32_16x16x32_bf16(a0, b, acc[0][nt], 0, 0, 0);
      acc[1][nt] = __builtin_amdgcn_mfma_f32_16x16x32_bf16(a1, b, acc[1][nt], 0, 0, 0);
    }
  }
  int col0 = lane & 15;
#pragma unroll
  for (int mt = 0; mt < 2; ++mt) {
    int rb = m0 + mt * 16 + ((lane >> 4) << 2);
#pragma unroll
    for (int nt = 0; nt < NT; ++nt) {
      int c = nt * 16 + col0;
      float bb = FIN ? bias[c] : 0.f;
#pragma unroll
      for (int r = 0; r < 4; ++r) {
        int row = rb + r;
        if (row < M) {
          float vv = acc[mt][nt][r] + bb;
          if (FIN) vv = fmaxf(vv, 0.f);
          outp[(size_t)row * NCOL + c] = vv;
        }
      }
    }
  }
}

extern "C" void kernel_launch(void* const* d_in, const int* in_sizes, int n_in,
                              void* d_out, int out_size, void* d_ws, size_t ws_size,
                              hipStream_t stream) {
  const float* x  = (const float*)d_in[0];
  const int*   ei = (const int*)d_in[1];
  const float* ea = (const float*)d_in[2];
  const float* Wg = (const float*)d_in[3];
  const float* bg = (const float*)d_in[4];
  const float* We = (const float*)d_in[5];
  const float* be = (const float*)d_in[6];
  const float* Wn = (const float*)d_in[7];
  const float* bn = (const float*)d_in[8];
  float* outp = (float*)d_out;
  int N = in_sizes[0] / DN;  // 50000
  int E = in_sizes[1] / 2;   // 800000

  char* p = (char*)d_ws;
  auto carve = [&](size_t bytes) {
    char* r = p;
    p += (bytes + 255) & ~(size_t)255;
    return (void*)r;
  };
  float* w     = (float*)carve((size_t)E * LE * 4);   // CSR-ordered latent weights
  float* xw    = (float*)carve((size_t)N * LN * 4);
  float* dinv  = (float*)carve((size_t)N * LE * 4);
  u16*   feats = (u16*)carve((size_t)N * (LE * LN) * 2);
  u16*   xb    = (u16*)carve((size_t)N * DN * 2);
  u16*   WnP   = (u16*)carve((size_t)(LE * LN) * DOUT * 2);
  u16*   WgP   = (u16*)carve((size_t)DN * LN * 2);
  int*   offs  = (int*)carve((size_t)(N + 1) * 4);
  int*   cnt   = (int*)carve((size_t)N * 4);
  int*   cur   = (int*)carve((size_t)N * 4);
  int*   src   = (int*)carve((size_t)E * 4);
  int*   epos  = (int*)carve((size_t)E * 4);

  hipMemsetAsync(cnt, 0, (size_t)N * 4, stream);
  hipMemsetAsync(cur, 0, (size_t)N * 4, stream);

  // CSR build
  k_count<<<(E + 255) / 256, 256, 0, stream>>>(ei, cnt, E);
  k_scan<<<1, 1024, 0, stream>>>(cnt, offs, N);
  k_fill<<<(E + 255) / 256, 256, 0, stream>>>(ei, cur, offs, epos, src, E);
  // edge MLP directly into CSR order
  k_edge_props<<<(E + 255) / 256, 256, 0, stream>>>(ea, We, be, epos, w, E);
  // node GEMM path (independent)
  k_f2bf<<<((N * DN / 4) + 255) / 256, 256, 0, stream>>>(x, xb, N * DN / 4);
  k_packb<<<(((DN / 32) * (LN / 16) * 64) + 255) / 256, 256, 0, stream>>>(Wg, WgP, DN, LN);
  k_packb<<<((((LE * LN) / 32) * (DOUT / 16) * 64) + 255) / 256, 256, 0, stream>>>(Wn, WnP, LE * LN, DOUT);
  k_gemm<DN, LN, false><<<(N + 127) / 128, 256, 0, stream>>>(xb, WgP, nullptr, xw, N);
  // normalization
  k_dinv<<<(N + 15) / 16, 256, 0, stream>>>(w, offs, dinv, N);
  k_wsc<<<((E * LE) + 255) / 256, 256, 0, stream>>>(w, src, dinv, E);
  // aggregation
  k_feats2<<<(N + 3) / 4, 256, 0, stream>>>(src, w, dinv, xw, bg, offs, feats, N);
  // output MLP
  k_gemm<LE * LN, DOUT, true><<<(N + 127) / 128, 256, 0, stream>>>(feats, WnP, bn, outp, N);
}

// Round 3
// 440.916 us; speedup vs baseline: 1.3041x; 1.0452x over previous
//
#include <hip/hip_runtime.h>
#include <hip/hip_bf16.h>

typedef short bf16x8 __attribute__((ext_vector_type(8)));
typedef float f32x4 __attribute__((ext_vector_type(4)));
typedef unsigned short u16;

#define DN 128   // node in props
#define DE 32    // edge in props
#define LE 16    // latent edges (channels)
#define LN 64    // latent nodes
#define DOUT 128 // out props

__device__ inline u16 f2bf(float f) {
  unsigned u = __float_as_uint(f);
  unsigned r = (u + 0x7FFFu + ((u >> 16) & 1u)) >> 16;
  return (u16)r;
}

__device__ inline void fma16(float c, const float4& a, const float4& b,
                             const float4& d, const float4& e, float* acc) {
  acc[0]  = fmaf(c, a.x, acc[0]);  acc[1]  = fmaf(c, a.y, acc[1]);
  acc[2]  = fmaf(c, a.z, acc[2]);  acc[3]  = fmaf(c, a.w, acc[3]);
  acc[4]  = fmaf(c, b.x, acc[4]);  acc[5]  = fmaf(c, b.y, acc[5]);
  acc[6]  = fmaf(c, b.z, acc[6]);  acc[7]  = fmaf(c, b.w, acc[7]);
  acc[8]  = fmaf(c, d.x, acc[8]);  acc[9]  = fmaf(c, d.y, acc[9]);
  acc[10] = fmaf(c, d.z, acc[10]); acc[11] = fmaf(c, d.w, acc[11]);
  acc[12] = fmaf(c, e.x, acc[12]); acc[13] = fmaf(c, e.y, acc[13]);
  acc[14] = fmaf(c, e.z, acc[14]); acc[15] = fmaf(c, e.w, acc[15]);
}

// w[epos[e], l] = relu(edge_attr[e,:] @ W_edge + b_edge)[l]  (CSR-ordered write)
__global__ __launch_bounds__(256) void k_edge_props(const float* __restrict__ ea,
    const float* __restrict__ We, const float* __restrict__ be,
    const int* __restrict__ epos, float* __restrict__ w, int E) {
  int e = blockIdx.x * 256 + threadIdx.x;
  if (e >= E) return;
  const float4* a4 = (const float4*)(ea + (size_t)e * DE);
  float a[DE];
#pragma unroll
  for (int j = 0; j < DE / 4; ++j) {
    float4 v = a4[j];
    a[4*j] = v.x; a[4*j+1] = v.y; a[4*j+2] = v.z; a[4*j+3] = v.w;
  }
  float acc[LE];
#pragma unroll
  for (int l = 0; l < LE; ++l) acc[l] = be[l];
#pragma unroll
  for (int k = 0; k < DE; ++k) {
    float av = a[k];
#pragma unroll
    for (int l = 0; l < LE; ++l) acc[l] = fmaf(av, We[k * LE + l], acc[l]);
  }
  float4* o4 = (float4*)(w + (size_t)epos[e] * LE);
#pragma unroll
  for (int j = 0; j < LE / 4; ++j) {
    float4 v;
    v.x = fmaxf(acc[4*j+0], 0.f); v.y = fmaxf(acc[4*j+1], 0.f);
    v.z = fmaxf(acc[4*j+2], 0.f); v.w = fmaxf(acc[4*j+3], 0.f);
    o4[j] = v;
  }
}

// Pack fp32 W[K,NCOL] into bf16 MFMA-B fragments:
// dst[((nt*KT+kt)*64+lane)*8+i] = W[kt*32+(lane>>4)*8+i][nt*16+(lane&15)]
__global__ __launch_bounds__(256) void k_packb(const float* __restrict__ W,
                                               u16* __restrict__ Bp, int K, int NCOL) {
  int NT = NCOL >> 4, KT = K >> 5;
  int total = NT * KT * 64;
  int idx = blockIdx.x * 256 + threadIdx.x;
  if (idx >= total) return;
  int lane = idx & 63;
  int rest = idx >> 6;
  int kt = rest % KT, nt = rest / KT;
  int col = nt * 16 + (lane & 15);
  int kb = kt * 32 + (lane >> 4) * 8;
  u16* dst = Bp + (size_t)idx * 8;
#pragma unroll
  for (int i = 0; i < 8; ++i) dst[i] = f2bf(W[(size_t)(kb + i) * NCOL + col]);
}

__global__ __launch_bounds__(256) void k_count(const int* __restrict__ ei,
                                               int* __restrict__ cnt, int E) {
  int e = blockIdx.x * 256 + threadIdx.x;
  if (e < E) atomicAdd(&cnt[ei[E + e]], 1);
}

// single-block exclusive scan over cnt[0..N) -> offs[0..N]
__global__ __launch_bounds__(1024) void k_scan(const int* __restrict__ cnt,
                                               int* __restrict__ offs, int N) {
  __shared__ int wsum[16];
  int t = threadIdx.x;
  int chunk = (N + 1023) >> 10;
  int s0 = t * chunk;
  int s1 = min(s0 + chunk, N);
  int s = 0;
  for (int i = s0; i < s1; ++i) s += cnt[i];
  int lane = t & 63, wid = t >> 6;
  int v = s;
#pragma unroll
  for (int d = 1; d < 64; d <<= 1) {
    int u = __shfl_up(v, d);
    if (lane >= d) v += u;
  }
  if (lane == 63) wsum[wid] = v;
  __syncthreads();
  if (t == 0) {
    int run = 0;
    for (int w = 0; w < 16; ++w) { int xv = wsum[w]; wsum[w] = run; run += xv; }
  }
  __syncthreads();
  int run = v - s + wsum[wid];  // exclusive prefix for this thread
  for (int i = s0; i < s1; ++i) { offs[i] = run; run += cnt[i]; }
  if (s1 == N && s0 < N) offs[N] = run;
}

// epos[e] = CSR slot of edge e; src[slot] = source node of that edge
__global__ __launch_bounds__(256) void k_fill(const int* __restrict__ ei,
    int* __restrict__ cur, const int* __restrict__ offs,
    int* __restrict__ epos, int* __restrict__ src, int E) {
  int e = blockIdx.x * 256 + threadIdx.x;
  if (e >= E) return;
  int c = ei[E + e];
  int p = atomicAdd(&cur[c], 1);
  int pos = offs[c] + p;
  epos[e] = pos;
  src[pos] = ei[e];
}

// dinv[n,l] = rsqrt(1 + sum over CSR segment of w[i,l])  (contiguous reads)
__global__ __launch_bounds__(256) void k_dinv(const float* __restrict__ w,
    const int* __restrict__ offs, float* __restrict__ dinv, int N) {
  int t = threadIdx.x;
  int n = blockIdx.x * 16 + (t >> 4);
  int l = t & 15;
  if (n >= N) return;
  int i0 = offs[n], i1 = offs[n + 1];
  float s = 1.0f;  // self loop weight
  for (int i = i0; i < i1; ++i) s += w[(size_t)i * LE + l];
  dinv[(size_t)n * LE + l] = rsqrtf(s);
}

// feats[n, l*64+c] = bf16( b_gcn[c] + dn*(sum_i w[i,l]*dinv[src_i,l]*xW[src_i,c]) + dn^2*xW[n,c] )
// one WAVE per node; lane = (l = lane&15, col group g = lane>>4, 16 cols each)
// 4-edge grouped software pipeline: ~24 loads in flight, next-group src prefetched
__global__ __launch_bounds__(256) void k_feats3(const int* __restrict__ src,
    const float* __restrict__ w, const float* __restrict__ dinv,
    const float* __restrict__ xw, const float* __restrict__ bgcn,
    const int* __restrict__ offs, u16* __restrict__ feats, int N) {
  int wid = threadIdx.x >> 6;
  int n = blockIdx.x * 4 + wid;
  if (n >= N) return;
  int lane = threadIdx.x & 63;
  int l = lane & 15, g = lane >> 4;
  float dn = dinv[(size_t)n * LE + l];
  const float* xbase = xw + g * 16;
  float acc[16];
#pragma unroll
  for (int j = 0; j < 16; ++j) acc[j] = 0.f;
  int i0 = offs[n], i1 = offs[n + 1];
  if (i0 < i1) {
    int rem = i1 - i0;
    int p1 = i0 + (rem > 1 ? 1 : 0);
    int p2 = i0 + (rem > 2 ? 2 : 0);
    int p3 = i0 + (rem > 3 ? 3 : 0);
    int s0 = src[i0], s1 = src[p1], s2 = src[p2], s3 = src[p3];
    for (int i = i0; i < i1; i += 4) {
      rem = i1 - i;
      // coefficient loads (w streams; dinv gathers hit L2: table is 3.2 MB)
      float c0 = w[(size_t)i * LE + l]  * dinv[(size_t)s0 * LE + l];
      float c1 = w[(size_t)p1 * LE + l] * dinv[(size_t)s1 * LE + l];
      float c2 = w[(size_t)p2 * LE + l] * dinv[(size_t)s2 * LE + l];
      float c3 = w[(size_t)p3 * LE + l] * dinv[(size_t)s3 * LE + l];
      if (rem < 2) c1 = 0.f;
      if (rem < 3) c2 = 0.f;
      if (rem < 4) c3 = 0.f;
      // xW row gathers for all 4 edges (16 float4 in flight)
      const float4* xr0 = (const float4*)(xbase + (size_t)s0 * LN);
      const float4* xr1 = (const float4*)(xbase + (size_t)s1 * LN);
      const float4* xr2 = (const float4*)(xbase + (size_t)s2 * LN);
      const float4* xr3 = (const float4*)(xbase + (size_t)s3 * LN);
      float4 A0 = xr0[0], A1 = xr0[1], A2 = xr0[2], A3 = xr0[3];
      float4 B0 = xr1[0], B1 = xr1[1], B2 = xr1[2], B3 = xr1[3];
      float4 C0 = xr2[0], C1 = xr2[1], C2 = xr2[2], C3 = xr2[3];
      float4 D0 = xr3[0], D1 = xr3[1], D2 = xr3[2], D3 = xr3[3];
      // prefetch next group's src while FMAs run
      int inx = i + 4;
      if (inx < i1) {
        int r2 = i1 - inx;
        p1 = inx + (r2 > 1 ? 1 : 0);
        p2 = inx + (r2 > 2 ? 2 : 0);
        p3 = inx + (r2 > 3 ? 3 : 0);
        s0 = src[inx]; s1 = src[p1]; s2 = src[p2]; s3 = src[p3];
      }
      fma16(c0, A0, A1, A2, A3, acc);
      fma16(c1, B0, B1, B2, B3, acc);
      fma16(c2, C0, C1, C2, C3, acc);
      fma16(c3, D0, D1, D2, D3, acc);
    }
  }
  float dn2 = dn * dn;
  const float4* xs4 = (const float4*)(xw + (size_t)n * LN + g * 16);
  const float4* bg4 = (const float4*)(bgcn + g * 16);
  u16* ob = feats + (size_t)n * (LE * LN) + l * LN + g * 16;
#pragma unroll
  for (int q = 0; q < 4; ++q) {
    float4 xs = xs4[q];
    float4 bg = bg4[q];
    short4 o;
    o.x = (short)f2bf(bg.x + dn * acc[4*q+0] + dn2 * xs.x);
    o.y = (short)f2bf(bg.y + dn * acc[4*q+1] + dn2 * xs.y);
    o.z = (short)f2bf(bg.z + dn * acc[4*q+2] + dn2 * xs.z);
    o.w = (short)f2bf(bg.w + dn * acc[4*q+3] + dn2 * xs.w);
    *(short4*)(ob + q * 4) = o;
  }
}

// C[M,NCOL] = A[M,K] @ Bpacked(bf16) (+bias, relu if FIN), fp32 out
// A is bf16 (AF32=false) or fp32 converted in-register (AF32=true)
// block: 4 waves, 32 rows/wave (MT=2), 128 rows/block
template <int K, int NCOL, bool FIN, bool AF32>
__global__ __launch_bounds__(256) void k_gemm(const void* __restrict__ Av,
    const u16* __restrict__ Bp, const float* __restrict__ bias,
    float* __restrict__ outp, int M) {
  constexpr int NT = NCOL / 16;
  constexpr int KT = K / 32;
  const u16* A16 = (const u16*)Av;
  const float* A32 = (const float*)Av;
  int lane = threadIdx.x & 63;
  int wid = threadIdx.x >> 6;
  int m0 = blockIdx.x * 128 + wid * 32;
  f32x4 acc[2][NT];
#pragma unroll
  for (int mt = 0; mt < 2; ++mt)
#pragma unroll
    for (int nt = 0; nt < NT; ++nt) {
      acc[mt][nt][0] = 0.f; acc[mt][nt][1] = 0.f;
      acc[mt][nt][2] = 0.f; acc[mt][nt][3] = 0.f;
    }
  int r0 = m0 + (lane & 15);
  int r1 = r0 + 16;
  bool v0 = r0 < M, v1 = r1 < M;
  int ko = (lane >> 4) * 8;
#pragma unroll 4
  for (int kt = 0; kt < KT; ++kt) {
    bf16x8 a0, a1;
#pragma unroll
    for (int i = 0; i < 8; ++i) { a0[i] = 0; a1[i] = 0; }
    if constexpr (AF32) {
      if (v0) {
        const float4* p4 = (const float4*)(A32 + (size_t)r0 * K + ko + kt * 32);
        float4 u0 = p4[0], u1 = p4[1];
        a0[0]=(short)f2bf(u0.x); a0[1]=(short)f2bf(u0.y); a0[2]=(short)f2bf(u0.z); a0[3]=(short)f2bf(u0.w);
        a0[4]=(short)f2bf(u1.x); a0[5]=(short)f2bf(u1.y); a0[6]=(short)f2bf(u1.z); a0[7]=(short)f2bf(u1.w);
      }
      if (v1) {
        const float4* p4 = (const float4*)(A32 + (size_t)r1 * K + ko + kt * 32);
        float4 u0 = p4[0], u1 = p4[1];
        a1[0]=(short)f2bf(u0.x); a1[1]=(short)f2bf(u0.y); a1[2]=(short)f2bf(u0.z); a1[3]=(short)f2bf(u0.w);
        a1[4]=(short)f2bf(u1.x); a1[5]=(short)f2bf(u1.y); a1[6]=(short)f2bf(u1.z); a1[7]=(short)f2bf(u1.w);
      }
    } else {
      if (v0) a0 = *(const bf16x8*)(A16 + (size_t)r0 * K + ko + kt * 32);
      if (v1) a1 = *(const bf16x8*)(A16 + (size_t)r1 * K + ko + kt * 32);
    }
#pragma unroll
    for (int nt = 0; nt < NT; ++nt) {
      bf16x8 b = *(const bf16x8*)(Bp + ((size_t)(nt * KT + kt) * 64 + lane) * 8);
      acc[0][nt] = __builtin_amdgcn_mfma_f32_16x16x32_bf16(a0, b, acc[0][nt], 0, 0, 0);
      acc[1][nt] = __builtin_amdgcn_mfma_f32_16x16x32_bf16(a1, b, acc[1][nt], 0, 0, 0);
    }
  }
  int col0 = lane & 15;
#pragma unroll
  for (int mt = 0; mt < 2; ++mt) {
    int rb = m0 + mt * 16 + ((lane >> 4) << 2);
#pragma unroll
    for (int nt = 0; nt < NT; ++nt) {
      int c = nt * 16 + col0;
      float bb = FIN ? bias[c] : 0.f;
#pragma unroll
      for (int r = 0; r < 4; ++r) {
        int row = rb + r;
        if (row < M) {
          float vv = acc[mt][nt][r] + bb;
          if (FIN) vv = fmaxf(vv, 0.f);
          outp[(size_t)row * NCOL + c] = vv;
        }
      }
    }
  }
}

extern "C" void kernel_launch(void* const* d_in, const int* in_sizes, int n_in,
                              void* d_out, int out_size, void* d_ws, size_t ws_size,
                              hipStream_t stream) {
  const float* x  = (const float*)d_in[0];
  const int*   ei = (const int*)d_in[1];
  const float* ea = (const float*)d_in[2];
  const float* Wg = (const float*)d_in[3];
  const float* bg = (const float*)d_in[4];
  const float* We = (const float*)d_in[5];
  const float* be = (const float*)d_in[6];
  const float* Wn = (const float*)d_in[7];
  const float* bn = (const float*)d_in[8];
  float* outp = (float*)d_out;
  int N = in_sizes[0] / DN;  // 50000
  int E = in_sizes[1] / 2;   // 800000

  char* p = (char*)d_ws;
  auto carve = [&](size_t bytes) {
    char* r = p;
    p += (bytes + 255) & ~(size_t)255;
    return (void*)r;
  };
  float* w     = (float*)carve((size_t)E * LE * 4);   // CSR-ordered latent weights
  float* xw    = (float*)carve((size_t)N * LN * 4);
  float* dinv  = (float*)carve((size_t)N * LE * 4);
  u16*   feats = (u16*)carve((size_t)N * (LE * LN) * 2);
  u16*   WnP   = (u16*)carve((size_t)(LE * LN) * DOUT * 2);
  u16*   WgP   = (u16*)carve((size_t)DN * LN * 2);
  int*   offs  = (int*)carve((size_t)(N + 1) * 4);
  int*   cnt   = (int*)carve((size_t)N * 4);
  int*   cur   = (int*)carve((size_t)N * 4);
  int*   src   = (int*)carve((size_t)E * 4);
  int*   epos  = (int*)carve((size_t)E * 4);

  hipMemsetAsync(cnt, 0, (size_t)N * 4, stream);
  hipMemsetAsync(cur, 0, (size_t)N * 4, stream);

  // CSR build
  k_count<<<(E + 255) / 256, 256, 0, stream>>>(ei, cnt, E);
  k_scan<<<1, 1024, 0, stream>>>(cnt, offs, N);
  k_fill<<<(E + 255) / 256, 256, 0, stream>>>(ei, cur, offs, epos, src, E);
  // edge MLP directly into CSR order
  k_edge_props<<<(E + 255) / 256, 256, 0, stream>>>(ea, We, be, epos, w, E);
  // node GEMM path (independent of edges)
  k_packb<<<(((DN / 32) * (LN / 16) * 64) + 255) / 256, 256, 0, stream>>>(Wg, WgP, DN, LN);
  k_packb<<<((((LE * LN) / 32) * (DOUT / 16) * 64) + 255) / 256, 256, 0, stream>>>(Wn, WnP, LE * LN, DOUT);
  k_gemm<DN, LN, false, true><<<(N + 127) / 128, 256, 0, stream>>>(x, WgP, nullptr, xw, N);
  // weighted in-degree normalization
  k_dinv<<<(N + 15) / 16, 256, 0, stream>>>(w, offs, dinv, N);
  // aggregation (dinv[src] folded in, 4-edge pipeline)
  k_feats3<<<(N + 3) / 4, 256, 0, stream>>>(src, w, dinv, xw, bg, offs, feats, N);
  // output MLP
  k_gemm<LE * LN, DOUT, true, false><<<(N + 127) / 128, 256, 0, stream>>>(feats, WnP, bn, outp, N);
}

// Round 4
// 385.678 us; speedup vs baseline: 1.4909x; 1.1432x over previous
//
#include <hip/hip_runtime.h>
#include <hip/hip_bf16.h>

typedef short bf16x8 __attribute__((ext_vector_type(8)));
typedef float f32x4 __attribute__((ext_vector_type(4)));
typedef unsigned short u16;

#define DN 128   // node in props
#define DE 32    // edge in props
#define LE 16    // latent edges (channels)
#define LN 64    // latent nodes
#define DOUT 128 // out props

__device__ inline u16 f2bf(float f) {
  unsigned u = __float_as_uint(f);
  unsigned r = (u + 0x7FFFu + ((u >> 16) & 1u)) >> 16;
  return (u16)r;
}
__device__ inline float bf2f(u16 h) {
  return __uint_as_float(((unsigned)h) << 16);
}
__device__ inline unsigned packbf(float lo, float hi) {
  return (unsigned)f2bf(lo) | ((unsigned)f2bf(hi) << 16);
}
// 8 bf16 packed in uint4 -> acc[0..7] += cf * val
__device__ inline void fma8h(float cf, const uint4& h, float* acc) {
  unsigned u;
  u = h.x;
  acc[0] = fmaf(cf, __uint_as_float(u << 16), acc[0]);
  acc[1] = fmaf(cf, __uint_as_float(u & 0xffff0000u), acc[1]);
  u = h.y;
  acc[2] = fmaf(cf, __uint_as_float(u << 16), acc[2]);
  acc[3] = fmaf(cf, __uint_as_float(u & 0xffff0000u), acc[3]);
  u = h.z;
  acc[4] = fmaf(cf, __uint_as_float(u << 16), acc[4]);
  acc[5] = fmaf(cf, __uint_as_float(u & 0xffff0000u), acc[5]);
  u = h.w;
  acc[6] = fmaf(cf, __uint_as_float(u << 16), acc[6]);
  acc[7] = fmaf(cf, __uint_as_float(u & 0xffff0000u), acc[7]);
}

// wb[epos[e], l] = bf16(relu(edge_attr[e,:] @ W_edge + b_edge)[l])  (CSR-ordered)
__global__ __launch_bounds__(256) void k_edge_props(const float* __restrict__ ea,
    const float* __restrict__ We, const float* __restrict__ be,
    const int* __restrict__ epos, u16* __restrict__ wb, int E) {
  int e = blockIdx.x * 256 + threadIdx.x;
  if (e >= E) return;
  const float4* a4 = (const float4*)(ea + (size_t)e * DE);
  float a[DE];
#pragma unroll
  for (int j = 0; j < DE / 4; ++j) {
    float4 v = a4[j];
    a[4*j] = v.x; a[4*j+1] = v.y; a[4*j+2] = v.z; a[4*j+3] = v.w;
  }
  float acc[LE];
#pragma unroll
  for (int l = 0; l < LE; ++l) acc[l] = be[l];
#pragma unroll
  for (int k = 0; k < DE; ++k) {
    float av = a[k];
#pragma unroll
    for (int l = 0; l < LE; ++l) acc[l] = fmaf(av, We[k * LE + l], acc[l]);
  }
  uint4 o0, o1;
  o0.x = packbf(fmaxf(acc[0], 0.f), fmaxf(acc[1], 0.f));
  o0.y = packbf(fmaxf(acc[2], 0.f), fmaxf(acc[3], 0.f));
  o0.z = packbf(fmaxf(acc[4], 0.f), fmaxf(acc[5], 0.f));
  o0.w = packbf(fmaxf(acc[6], 0.f), fmaxf(acc[7], 0.f));
  o1.x = packbf(fmaxf(acc[8], 0.f), fmaxf(acc[9], 0.f));
  o1.y = packbf(fmaxf(acc[10], 0.f), fmaxf(acc[11], 0.f));
  o1.z = packbf(fmaxf(acc[12], 0.f), fmaxf(acc[13], 0.f));
  o1.w = packbf(fmaxf(acc[14], 0.f), fmaxf(acc[15], 0.f));
  uint4* o4 = (uint4*)(wb + (size_t)epos[e] * LE);
  o4[0] = o0; o4[1] = o1;
}

// Pack fp32 W[K,NCOL] into bf16 MFMA-B fragments:
// dst[((nt*KT+kt)*64+lane)*8+i] = W[kt*32+(lane>>4)*8+i][nt*16+(lane&15)]
__global__ __launch_bounds__(256) void k_packb(const float* __restrict__ W,
                                               u16* __restrict__ Bp, int K, int NCOL) {
  int NT = NCOL >> 4, KT = K >> 5;
  int total = NT * KT * 64;
  int idx = blockIdx.x * 256 + threadIdx.x;
  if (idx >= total) return;
  int lane = idx & 63;
  int rest = idx >> 6;
  int kt = rest % KT, nt = rest / KT;
  int col = nt * 16 + (lane & 15);
  int kb = kt * 32 + (lane >> 4) * 8;
  u16* dst = Bp + (size_t)idx * 8;
#pragma unroll
  for (int i = 0; i < 8; ++i) dst[i] = f2bf(W[(size_t)(kb + i) * NCOL + col]);
}

__global__ __launch_bounds__(256) void k_count(const int* __restrict__ ei,
                                               int* __restrict__ cnt, int E) {
  int e = blockIdx.x * 256 + threadIdx.x;
  if (e < E) atomicAdd(&cnt[ei[E + e]], 1);
}

// single-block exclusive scan over cnt[0..N) -> offs[0..N]
__global__ __launch_bounds__(1024) void k_scan(const int* __restrict__ cnt,
                                               int* __restrict__ offs, int N) {
  __shared__ int wsum[16];
  int t = threadIdx.x;
  int chunk = (N + 1023) >> 10;
  int s0 = t * chunk;
  int s1 = min(s0 + chunk, N);
  int s = 0;
  for (int i = s0; i < s1; ++i) s += cnt[i];
  int lane = t & 63, wid = t >> 6;
  int v = s;
#pragma unroll
  for (int d = 1; d < 64; d <<= 1) {
    int u = __shfl_up(v, d);
    if (lane >= d) v += u;
  }
  if (lane == 63) wsum[wid] = v;
  __syncthreads();
  if (t == 0) {
    int run = 0;
    for (int w = 0; w < 16; ++w) { int xv = wsum[w]; wsum[w] = run; run += xv; }
  }
  __syncthreads();
  int run = v - s + wsum[wid];  // exclusive prefix for this thread
  for (int i = s0; i < s1; ++i) { offs[i] = run; run += cnt[i]; }
  if (s1 == N && s0 < N) offs[N] = run;
}

// epos[e] = CSR slot of edge e; src[slot] = source node of that edge
__global__ __launch_bounds__(256) void k_fill(const int* __restrict__ ei,
    int* __restrict__ cur, const int* __restrict__ offs,
    int* __restrict__ epos, int* __restrict__ src, int E) {
  int e = blockIdx.x * 256 + threadIdx.x;
  if (e >= E) return;
  int c = ei[E + e];
  int p = atomicAdd(&cur[c], 1);
  int pos = offs[c] + p;
  epos[e] = pos;
  src[pos] = ei[e];
}

// dinv[n,l] = rsqrt(1 + sum over CSR segment of wb[i,l])
__global__ __launch_bounds__(256) void k_dinv(const u16* __restrict__ wb,
    const int* __restrict__ offs, float* __restrict__ dinv, int N) {
  int t = threadIdx.x;
  int n = blockIdx.x * 16 + (t >> 4);
  int l = t & 15;
  if (n >= N) return;
  int i0 = offs[n], i1 = offs[n + 1];
  float s = 1.0f;  // self loop weight
  for (int i = i0; i < i1; ++i) s += bf2f(wb[(size_t)i * LE + l]);
  dinv[(size_t)n * LE + l] = rsqrtf(s);
}

// C[M,NCOL] = A[M,K] @ Bpacked(bf16) (+bias, relu if FIN)
// A fp32 converted in-register (AF32) or bf16; out fp32 or bf16 (OUT16)
template <int K, int NCOL, bool FIN, bool AF32, bool OUT16>
__global__ __launch_bounds__(256) void k_gemm(const void* __restrict__ Av,
    const u16* __restrict__ Bp, const float* __restrict__ bias,
    void* __restrict__ outv, int M) {
  constexpr int NT = NCOL / 16;
  constexpr int KT = K / 32;
  const u16* A16 = (const u16*)Av;
  const float* A32 = (const float*)Av;
  int lane = threadIdx.x & 63;
  int wid = threadIdx.x >> 6;
  int m0 = blockIdx.x * 128 + wid * 32;
  f32x4 acc[2][NT];
#pragma unroll
  for (int mt = 0; mt < 2; ++mt)
#pragma unroll
    for (int nt = 0; nt < NT; ++nt) {
      acc[mt][nt][0] = 0.f; acc[mt][nt][1] = 0.f;
      acc[mt][nt][2] = 0.f; acc[mt][nt][3] = 0.f;
    }
  int r0 = m0 + (lane & 15);
  int r1 = r0 + 16;
  bool v0 = r0 < M, v1 = r1 < M;
  int ko = (lane >> 4) * 8;
#pragma unroll 4
  for (int kt = 0; kt < KT; ++kt) {
    bf16x8 a0, a1;
#pragma unroll
    for (int i = 0; i < 8; ++i) { a0[i] = 0; a1[i] = 0; }
    if constexpr (AF32) {
      if (v0) {
        const float4* p4 = (const float4*)(A32 + (size_t)r0 * K + ko + kt * 32);
        float4 u0 = p4[0], u1 = p4[1];
        a0[0]=(short)f2bf(u0.x); a0[1]=(short)f2bf(u0.y); a0[2]=(short)f2bf(u0.z); a0[3]=(short)f2bf(u0.w);
        a0[4]=(short)f2bf(u1.x); a0[5]=(short)f2bf(u1.y); a0[6]=(short)f2bf(u1.z); a0[7]=(short)f2bf(u1.w);
      }
      if (v1) {
        const float4* p4 = (const float4*)(A32 + (size_t)r1 * K + ko + kt * 32);
        float4 u0 = p4[0], u1 = p4[1];
        a1[0]=(short)f2bf(u0.x); a1[1]=(short)f2bf(u0.y); a1[2]=(short)f2bf(u0.z); a1[3]=(short)f2bf(u0.w);
        a1[4]=(short)f2bf(u1.x); a1[5]=(short)f2bf(u1.y); a1[6]=(short)f2bf(u1.z); a1[7]=(short)f2bf(u1.w);
      }
    } else {
      if (v0) a0 = *(const bf16x8*)(A16 + (size_t)r0 * K + ko + kt * 32);
      if (v1) a1 = *(const bf16x8*)(A16 + (size_t)r1 * K + ko + kt * 32);
    }
#pragma unroll
    for (int nt = 0; nt < NT; ++nt) {
      bf16x8 b = *(const bf16x8*)(Bp + ((size_t)(nt * KT + kt) * 64 + lane) * 8);
      acc[0][nt] = __builtin_amdgcn_mfma_f32_16x16x32_bf16(a0, b, acc[0][nt], 0, 0, 0);
      acc[1][nt] = __builtin_amdgcn_mfma_f32_16x16x32_bf16(a1, b, acc[1][nt], 0, 0, 0);
    }
  }
  int col0 = lane & 15;
#pragma unroll
  for (int mt = 0; mt < 2; ++mt) {
    int rb = m0 + mt * 16 + ((lane >> 4) << 2);
#pragma unroll
    for (int nt = 0; nt < NT; ++nt) {
      int c = nt * 16 + col0;
      float bb = FIN ? bias[c] : 0.f;
#pragma unroll
      for (int r = 0; r < 4; ++r) {
        int row = rb + r;
        if (row < M) {
          float vv = acc[mt][nt][r] + bb;
          if (FIN) vv = fmaxf(vv, 0.f);
          if constexpr (OUT16) ((u16*)outv)[(size_t)row * NCOL + c] = f2bf(vv);
          else ((float*)outv)[(size_t)row * NCOL + c] = vv;
        }
      }
    }
  }
}

// Fused: GCN aggregation (gather) -> feats row in LDS (bf16) -> MFMA output MLP
// block = 16 nodes (4 waves x 4 nodes); lane: l = lane&15 (channel), g = lane>>4
// LDS row stride 2064 B (pad 16 B) + XOR swizzle ((l&7)<<4) on within-row byte offset
__global__ __launch_bounds__(256) void k_fused(const int* __restrict__ src,
    const u16* __restrict__ wb, const float* __restrict__ dinv,
    const u16* __restrict__ xwb, const float* __restrict__ bgcn,
    const int* __restrict__ offs, const u16* __restrict__ WnP,
    const float* __restrict__ bn, float* __restrict__ y, int N) {
  __shared__ char Sm[16 * 2064];
  int tid = threadIdx.x;
  int wid = tid >> 6, lane = tid & 63;
  int l = lane & 15, g = lane >> 4;
  int nblk = blockIdx.x * 16;
  // ---- gather phase: 4 nodes per wave ----
  for (int q = 0; q < 4; ++q) {
    int r = wid * 4 + q;
    int n = nblk + r;
    bool valid = n < N;
    float acc[16];
#pragma unroll
    for (int j = 0; j < 16; ++j) acc[j] = 0.f;
    float dn = 1.f;
    if (valid) {
      dn = dinv[(size_t)n * LE + l];
      int i0 = offs[n], i1 = offs[n + 1];
      int sA = (i0 < i1) ? src[i0] : 0;
      for (int i = i0; i < i1; ++i) {
        int s = sA;
        float wv = bf2f(wb[(size_t)i * LE + l]);
        float dv = dinv[(size_t)s * LE + l];
        const uint4* xr = (const uint4*)(xwb + (size_t)s * LN + g * 16);
        uint4 h0 = xr[0], h1 = xr[1];
        if (i + 1 < i1) sA = src[i + 1];
        float cf = wv * dv;
        fma8h(cf, h0, acc);
        fma8h(cf, h1, acc + 8);
      }
    }
    // epilogue -> LDS (bf16)
    float dn2 = dn * dn;
    int nn = valid ? n : 0;
    const uint4* xs = (const uint4*)(xwb + (size_t)nn * LN + g * 16);
    uint4 m0 = xs[0], m1 = xs[1];
    const float4* bg4 = (const float4*)(bgcn + g * 16);
    float4 b0 = bg4[0], b1 = bg4[1], b2 = bg4[2], b3 = bg4[3];
    float xv[16];
    xv[0] = __uint_as_float(m0.x << 16); xv[1] = __uint_as_float(m0.x & 0xffff0000u);
    xv[2] = __uint_as_float(m0.y << 16); xv[3] = __uint_as_float(m0.y & 0xffff0000u);
    xv[4] = __uint_as_float(m0.z << 16); xv[5] = __uint_as_float(m0.z & 0xffff0000u);
    xv[6] = __uint_as_float(m0.w << 16); xv[7] = __uint_as_float(m0.w & 0xffff0000u);
    xv[8] = __uint_as_float(m1.x << 16); xv[9] = __uint_as_float(m1.x & 0xffff0000u);
    xv[10] = __uint_as_float(m1.y << 16); xv[11] = __uint_as_float(m1.y & 0xffff0000u);
    xv[12] = __uint_as_float(m1.z << 16); xv[13] = __uint_as_float(m1.z & 0xffff0000u);
    xv[14] = __uint_as_float(m1.w << 16); xv[15] = __uint_as_float(m1.w & 0xffff0000u);
    float bgv[16] = {b0.x,b0.y,b0.z,b0.w,b1.x,b1.y,b1.z,b1.w,
                     b2.x,b2.y,b2.z,b2.w,b3.x,b3.y,b3.z,b3.w};
    float ov[16];
#pragma unroll
    for (int j = 0; j < 16; ++j) ov[j] = bgv[j] + dn * acc[j] + dn2 * xv[j];
    uint4 o0, o1;
    o0.x = packbf(ov[0], ov[1]);  o0.y = packbf(ov[2], ov[3]);
    o0.z = packbf(ov[4], ov[5]);  o0.w = packbf(ov[6], ov[7]);
    o1.x = packbf(ov[8], ov[9]);  o1.y = packbf(ov[10], ov[11]);
    o1.z = packbf(ov[12], ov[13]); o1.w = packbf(ov[14], ov[15]);
    int off = l * 128 + g * 32;  // byte offset within feats row
    int swz = (l & 7) << 4;
    char* rowp = Sm + r * 2064;
    *(uint4*)(rowp + (off ^ swz)) = o0;
    *(uint4*)(rowp + ((off + 16) ^ swz)) = o1;
  }
  __syncthreads();
  // ---- MFMA phase: y[16,128] = S[16,1024] @ Wn ----
  f32x4 acc2[2];
#pragma unroll
  for (int t = 0; t < 2; ++t) {
    acc2[t][0] = 0.f; acc2[t][1] = 0.f; acc2[t][2] = 0.f; acc2[t][3] = 0.f;
  }
  int ar = lane & 15;
  const char* arow = Sm + ar * 2064;
#pragma unroll 8
  for (int kt = 0; kt < 32; ++kt) {
    int aoff = kt * 64 + g * 16;
    int key = ((aoff >> 7) & 7) << 4;
    bf16x8 a = *(const bf16x8*)(arow + (aoff ^ key));
    bf16x8 bA = *(const bf16x8*)(WnP + ((size_t)((wid * 2 + 0) * 32 + kt) * 64 + lane) * 8);
    bf16x8 bB = *(const bf16x8*)(WnP + ((size_t)((wid * 2 + 1) * 32 + kt) * 64 + lane) * 8);
    acc2[0] = __builtin_amdgcn_mfma_f32_16x16x32_bf16(a, bA, acc2[0], 0, 0, 0);
    acc2[1] = __builtin_amdgcn_mfma_f32_16x16x32_bf16(a, bB, acc2[1], 0, 0, 0);
  }
  int col0 = lane & 15;
  int rowb = nblk + (lane >> 4) * 4;
#pragma unroll
  for (int t = 0; t < 2; ++t) {
    int c = (wid * 2 + t) * 16 + col0;
    float bb = bn[c];
#pragma unroll
    for (int rr = 0; rr < 4; ++rr) {
      int row = rowb + rr;
      if (row < N) y[(size_t)row * DOUT + c] = fmaxf(acc2[t][rr] + bb, 0.f);
    }
  }
}

extern "C" void kernel_launch(void* const* d_in, const int* in_sizes, int n_in,
                              void* d_out, int out_size, void* d_ws, size_t ws_size,
                              hipStream_t stream) {
  const float* x  = (const float*)d_in[0];
  const int*   ei = (const int*)d_in[1];
  const float* ea = (const float*)d_in[2];
  const float* Wg = (const float*)d_in[3];
  const float* bg = (const float*)d_in[4];
  const float* We = (const float*)d_in[5];
  const float* be = (const float*)d_in[6];
  const float* Wn = (const float*)d_in[7];
  const float* bn = (const float*)d_in[8];
  float* outp = (float*)d_out;
  int N = in_sizes[0] / DN;  // 50000
  int E = in_sizes[1] / 2;   // 800000

  char* p = (char*)d_ws;
  auto carve = [&](size_t bytes) {
    char* r = p;
    p += (bytes + 255) & ~(size_t)255;
    return (void*)r;
  };
  u16*   wb    = (u16*)carve((size_t)E * LE * 2);    // CSR-ordered latent weights, bf16
  u16*   xwb   = (u16*)carve((size_t)N * LN * 2);    // xW in bf16
  float* dinv  = (float*)carve((size_t)N * LE * 4);
  u16*   WnP   = (u16*)carve((size_t)(LE * LN) * DOUT * 2);
  u16*   WgP   = (u16*)carve((size_t)DN * LN * 2);
  int*   offs  = (int*)carve((size_t)(N + 1) * 4);
  int*   cnt   = (int*)carve((size_t)N * 4);
  int*   cur   = (int*)carve((size_t)N * 4);
  int*   src   = (int*)carve((size_t)E * 4);
  int*   epos  = (int*)carve((size_t)E * 4);

  hipMemsetAsync(cnt, 0, (size_t)N * 4, stream);
  hipMemsetAsync(cur, 0, (size_t)N * 4, stream);

  // CSR build
  k_count<<<(E + 255) / 256, 256, 0, stream>>>(ei, cnt, E);
  k_scan<<<1, 1024, 0, stream>>>(cnt, offs, N);
  k_fill<<<(E + 255) / 256, 256, 0, stream>>>(ei, cur, offs, epos, src, E);
  // edge MLP directly into CSR order (bf16)
  k_edge_props<<<(E + 255) / 256, 256, 0, stream>>>(ea, We, be, epos, wb, E);
  // node GEMM path (independent of edges): xW in bf16
  k_packb<<<(((DN / 32) * (LN / 16) * 64) + 255) / 256, 256, 0, stream>>>(Wg, WgP, DN, LN);
  k_packb<<<((((LE * LN) / 32) * (DOUT / 16) * 64) + 255) / 256, 256, 0, stream>>>(Wn, WnP, LE * LN, DOUT);
  k_gemm<DN, LN, false, true, true><<<(N + 127) / 128, 256, 0, stream>>>(x, WgP, nullptr, xwb, N);
  // weighted in-degree normalization
  k_dinv<<<(N + 15) / 16, 256, 0, stream>>>(wb, offs, dinv, N);
  // fused aggregation + output MLP
  k_fused<<<(N + 15) / 16, 256, 0, stream>>>(src, wb, dinv, xwb, bg, offs, WnP, bn, outp, N);
}